// Round 21
// baseline (60.073 us; speedup 1.0000x reference)
//
#include <hip/hip_runtime.h>
#include <math.h>

#define NB 8
#define NC 3
#define HH 144
#define WW 144
#define NPAT 2304            // 48*48 patches per 144x144 image
#define NPTOT (NB * NPAT)    // 18432
#define MCAT 3024            // real candidates: 2304 + 576 + 144
#define MCATP 3072           // padded (48 guard cols, T = 1e30)
#define SPLITS 3             // candidate thirds (traffic is SPLITS-independent)
#define CSPLIT 1024          // candidates per split
#define STEPS 8              // CSPLIT / (64 lanes * 2 cands)
#define PPT 9                // patches per 64-lane wave (aa2 -> 81 SGPRs via s_load)
#define WAVES 4              // waves per 256-thread block
#define PPB (PPT * WAVES)    // 36 patches per block
#define BLOCKS_PER_B (NPAT / PPB)                 // 64
#define NBLK_SCORE (NB * BLOCKS_PER_B * SPLITS)   // 1536
#define NBLK_MERGE (NPTOT / 256)                  // 72

typedef float f2 __attribute__((ext_vector_type(2)));

__device__ __forceinline__ int iclamp(int v, int lo, int hi) {
    return v < lo ? lo : (v > hi ? hi : v);
}

// ---- fully fused bicubic resize (H then W pass per output pixel, frac=0.5
// constant taps; H-pass partials recomputed per pixel in identical fp32 order)
__global__ void resize_all(const float* __restrict__ gt,
                           float* __restrict__ gt2, float* __restrict__ gt4) {
    const int T2 = NB * NC * 72 * 72;
    const int T4 = NB * NC * 36 * 36;
    int idx = blockIdx.x * blockDim.x + threadIdx.x;
    if (idx >= T2 + T4) return;
    int scale, HO, WO;
    float* dst;
    int li;
    if (idx < T2) { scale = 2; HO = 72; WO = 72; dst = gt2; li = idx; }
    else          { scale = 4; HO = 36; WO = 36; dst = gt4; li = idx - T2; }
    int w  = li % WO;
    int h  = (li / WO) % HO;
    int bc = li / (WO * HO);
    const float* G = gt + (size_t)bc * HH * WW;
    int tr = scale * h + (scale >> 1) - 2;
    int tc = scale * w + (scale >> 1) - 2;
    int r0 = iclamp(tr + 0, 0, HH - 1) * WW;
    int r1 = iclamp(tr + 1, 0, HH - 1) * WW;
    int r2 = iclamp(tr + 2, 0, HH - 1) * WW;
    int r3 = iclamp(tr + 3, 0, HH - 1) * WW;
    float acc = 0.0f;
#pragma unroll
    for (int cc = 0; cc < 4; cc++) {
        int col = iclamp(tc + cc, 0, WW - 1);
        float hv = 0.0f;                       // H-pass value (same order as 2-pass)
        hv += -0.09375f * G[r0 + col];
        hv +=  0.59375f * G[r1 + col];
        hv +=  0.59375f * G[r2 + col];
        hv += -0.09375f * G[r3 + col];
        float wt = (cc == 0 || cc == 3) ? -0.09375f : 0.59375f;
        acc += wt * hv;                        // W-pass, same order
    }
    dst[li] = acc;
}

// gram of one 3x3 patch -> 9 values, /27 (same op order as reference)
__device__ __forceinline__ void patch_gram(const float* __restrict__ src, int H, int W,
                                           int b, int n, float* __restrict__ g) {
    int PW = W / 3;
    int ph = n / PW, pw = n % PW;
    float p[3][9];
#pragma unroll
    for (int c = 0; c < 3; c++) {
        const float* s = src + ((size_t)b * NC + c) * H * W + (size_t)(ph * 3) * W + pw * 3;
#pragma unroll
        for (int i = 0; i < 3; i++)
#pragma unroll
            for (int j = 0; j < 3; j++)
                p[c][i * 3 + j] = s[i * W + j];
    }
#pragma unroll
    for (int c = 0; c < 3; c++)
#pragma unroll
        for (int e = 0; e < 3; e++) {
            float s = 0.0f;
#pragma unroll
            for (int q = 0; q < 9; q++) s += p[c][q] * p[e][q];
            g[c * 3 + e] = s / 27.0f;
        }
}

// store candidate gram transposed [b][10][MCATP]; row 9 = T = 2*y2
__device__ __forceinline__ void store_cand(float* __restrict__ p2cT, int b, int m,
                                           const float g[9]) {
    float y2 = 0.0f;
#pragma unroll
    for (int j = 0; j < 9; j++) {
        p2cT[((size_t)b * 10 + j) * MCATP + m] = g[j];
        y2 += g[j] * g[j];
    }
    p2cT[((size_t)b * 10 + 9) * MCATP + m] = 2.0f * y2;
}

// ---- patches: fully independent threads (R16-verified fast); 43008 threads,
// 27 loads each.  pw is built by aa2_kernel afterwards.
__global__ void patch_all(const float* __restrict__ x, const float* __restrict__ gt,
                          const float* __restrict__ gt2, const float* __restrict__ gt4,
                          float* __restrict__ p1, float* __restrict__ p2cT) {
    const int R0 = NPTOT;        // x   -> p1
    const int R1 = NPTOT;        // gt  -> cand m = n
    const int R2 = NB * 576;     // gt2 -> m = 2304 + n
    const int R3 = NB * 144;     // gt4 -> m = 2880 + n
    int idx = blockIdx.x * blockDim.x + threadIdx.x;
    if (idx >= R0 + R1 + R2 + R3 + NB * 48) return;

    float g[9];
    if (idx < R0) {
        int b = idx / NPAT, n = idx % NPAT;
        patch_gram(x, 144, 144, b, n, g);
        float* d = p1 + (size_t)idx * 9;
#pragma unroll
        for (int j = 0; j < 9; j++) d[j] = g[j];
        return;
    }
    if (idx < R0 + R1) {
        int li = idx - R0;
        int b = li / NPAT, n = li % NPAT;
        patch_gram(gt, 144, 144, b, n, g);
        store_cand(p2cT, b, n, g);
        return;
    }
    if (idx < R0 + R1 + R2) {
        int li = idx - R0 - R1;
        int b = li / 576, n = li % 576;
        patch_gram(gt2, 72, 72, b, n, g);
        store_cand(p2cT, b, NPAT + n, g);
        return;
    }
    if (idx < R0 + R1 + R2 + R3) {
        int li = idx - R0 - R1 - R2;
        int b = li / 144, n = li % 144;
        patch_gram(gt4, 36, 36, b, n, g);
        store_cand(p2cT, b, NPAT + 576 + n, g);
        return;
    }
    // guard columns: cand = 0, T = 1e30 (never wins)
    {
        int li = idx - R0 - R1 - R2 - R3;
        int b = li / 48, m = MCAT + li % 48;
#pragma unroll
        for (int j = 0; j < 9; j++) p2cT[((size_t)b * 10 + j) * MCATP + m] = 0.0f;
        p2cT[((size_t)b * 10 + 9) * MCATP + m] = 1e30f;
    }
}

// ---- build the aa2 table: pw[gp][j] = -2*(p1[gp][j] + p2[gp][j]).
__global__ void aa2_kernel(const float* __restrict__ p1, const float* __restrict__ p2cT,
                           float* __restrict__ pw) {
    int gp = blockIdx.x * blockDim.x + threadIdx.x;
    if (gp >= NPTOT) return;
    int b = gp / NPAT, n = gp % NPAT;
    const float* P1 = p1 + (size_t)gp * 9;
    const float* PB = p2cT + (size_t)b * 10 * MCATP;
    float* W = pw + (size_t)gp * 12;
#pragma unroll
    for (int j = 0; j < 9; j++)
        W[j] = -2.0f * (P1[j] + PB[(size_t)j * MCATP + n]);
}

// ---- score + argmin over one candidate THIRD, straight from L2 (NO LDS, NO
// barriers).  sc' = T + sum_j aa2[j]*v[j].
// R20->R21 single-variable experiment: STEPS loop unroll 1 -> 2.  Theory:
// score is pinned at ~40us across all configs because at VGPR=32 there is no
// headroom to keep the NEXT step's 10 loads in flight -- each step exposes
// (L2 latency - argmin issue) of naked stall.  Unroll-2 batches two steps'
// 20 loads; VGPR rises to ~70-90 (4 waves/SIMD bracket -- deliberate trade).
// Per-candidate math + sequential ascending-index argmin unchanged.
__global__ __launch_bounds__(256) void score_kernel(const float* __restrict__ p2cT,
                                                    const float* __restrict__ pw,
                                                    float* __restrict__ best_s,
                                                    int* __restrict__ best_i) {
    int t     = threadIdx.x;
    int lane  = t & 63;
    int wv    = t >> 6;
    int blk   = blockIdx.x;
    int b     = blk / (SPLITS * BLOCKS_PER_B);
    int r     = blk % (SPLITS * BLOCKS_PER_B);
    int split = r / BLOCKS_PER_B;
    int bb    = r % BLOCKS_PER_B;
    int nbase = bb * PPB + wv * PPT;

    const float* PB = p2cT + (size_t)b * 10 * MCATP;

    // scalar base index (SGPR) -> all aa2 loads are s_load into SGPRs
    int gp0 = __builtin_amdgcn_readfirstlane(b * NPAT + nbase);
    const float* W0 = pw + (size_t)gp0 * 12;
    float aa2[PPT][9];
#pragma unroll
    for (int p = 0; p < PPT; p++)
#pragma unroll
        for (int j = 0; j < 9; j++) aa2[p][j] = W0[p * 12 + j];

    float best[PPT];
    int   besti[PPT];
#pragma unroll
    for (int p = 0; p < PPT; p++) { best[p] = INFINITY; besti[p] = 0x7fffffff; }

    int cb = split * CSPLIT;
#pragma unroll 2
    for (int st = 0; st < STEPS; st++) {
        int cl = cb + st * 128 + lane * 2;          // even float index, 8B aligned
        f2 Tv = *(const f2*)&PB[(size_t)9 * MCATP + cl];
        f2 s[PPT];
#pragma unroll
        for (int p = 0; p < PPT; p++) s[p] = Tv;
#pragma unroll
        for (int j = 0; j < 9; j++) {
            f2 v = *(const f2*)&PB[(size_t)j * MCATP + cl];
#pragma unroll
            for (int p = 0; p < PPT; p++) s[p] += aa2[p][j] * v;   // v_pk_fma v,s,v
        }
#pragma unroll
        for (int p = 0; p < PPT; p++) {
            // min3 + guarded select; x tested first -> first-min tie-break
            float nb = fminf(fminf(best[p], s[p].x), s[p].y);
            if (nb < best[p]) {
                besti[p] = (nb == s[p].x) ? cl : cl + 1;
                best[p]  = nb;
            }
        }
    }

    // lexicographic (score, idx) min across the 64 lanes
#pragma unroll
    for (int p = 0; p < PPT; p++) {
#pragma unroll
        for (int m = 1; m < 64; m <<= 1) {
            float ob = __shfl_xor(best[p], m);
            int   oi = __shfl_xor(besti[p], m);
            if (ob < best[p] || (ob == best[p] && oi < besti[p])) { best[p] = ob; besti[p] = oi; }
        }
        if (lane == 0) {
            size_t o = (size_t)split * NPTOT + (size_t)b * NPAT + nbase + p;
            best_s[o] = best[p];
            best_i[o] = besti[p];
        }
    }
}

// ---- merge the three split results + per-patch L1 + per-block partial sum
__global__ __launch_bounds__(256) void merge_kernel(const float* __restrict__ p1,
                                                    const float* __restrict__ p2cT,
                                                    const float* __restrict__ best_s,
                                                    const int* __restrict__ best_i,
                                                    float* __restrict__ parts) {
    __shared__ float wsum[4];
    int t  = threadIdx.x;
    int gp = blockIdx.x * 256 + t;
    int b  = gp / NPAT;
    float bs = best_s[gp];
    int   bi = best_i[gp];
    // strict < : earlier split (lower indices) wins ties
    float s1 = best_s[NPTOT + gp];
    int   i1 = best_i[NPTOT + gp];
    if (s1 < bs) { bs = s1; bi = i1; }
    float s2 = best_s[2 * NPTOT + gp];
    int   i2 = best_i[2 * NPTOT + gp];
    if (s2 < bs) { bs = s2; bi = i2; }
    const float* P1 = p1 + (size_t)gp * 9;
    const float* PB = p2cT + (size_t)b * 10 * MCATP;
    float l = 0.0f;
#pragma unroll
    for (int j = 0; j < 9; j++) l += fabsf(P1[j] - PB[(size_t)j * MCATP + bi]);
#pragma unroll
    for (int m = 1; m < 64; m <<= 1) l += __shfl_xor(l, m);
    if ((t & 63) == 0) wsum[t >> 6] = l;
    __syncthreads();
    if (t == 0) parts[blockIdx.x] = (wsum[0] + wsum[1]) + (wsum[2] + wsum[3]);
}

__global__ void final_kernel(const float* __restrict__ parts, float* __restrict__ out) {
    int lane = threadIdx.x;
    float s = 0.0f;
    for (int i = lane; i < NBLK_MERGE; i += 64) s += parts[i];
#pragma unroll
    for (int m = 1; m < 64; m <<= 1) s += __shfl_xor(s, m);
    if (lane == 0) out[0] = s / 165888.0f;   // mean over 8*2304*9
}

extern "C" void kernel_launch(void* const* d_in, const int* in_sizes, int n_in,
                              void* d_out, int out_size, void* d_ws, size_t ws_size,
                              hipStream_t stream) {
    const float* x  = (const float*)d_in[0];
    const float* gt = (const float*)d_in[1];
    float* out = (float*)d_out;

    float* ws     = (float*)d_ws;
    float* gt2    = ws;                               // [8,3,72,72]   = 124416
    float* gt4    = gt2  + NB * NC * 72 * 72;         // [8,3,36,36]   =  31104
    float* p1     = gt4  + NB * NC * 36 * 36;         // [18432,9]     = 165888
    float* p2cT   = p1 + (size_t)NPTOT * 9;           // [8,10,3072]   = 245760
    float* pw     = p2cT + (size_t)NB * 10 * MCATP;   // [18432,12]    = 221184
    float* best_s = pw + (size_t)NPTOT * 12;          // [3,18432]     =  55296
    int*   best_i = (int*)(best_s + SPLITS * NPTOT);  // [3,18432]     =  55296
    float* parts  = (float*)(best_i + SPLITS * NPTOT);// [72]

    {
        int tot = NB * NC * 72 * 72 + NB * NC * 36 * 36;   // 155520
        resize_all<<<(tot + 255) / 256, 256, 0, stream>>>(gt, gt2, gt4);
    }
    {
        int tot = NPTOT + NPTOT + NB * 576 + NB * 144 + NB * 48;   // 43008
        patch_all<<<(tot + 255) / 256, 256, 0, stream>>>(x, gt, gt2, gt4, p1, p2cT);
    }
    aa2_kernel<<<(NPTOT + 255) / 256, 256, 0, stream>>>(p1, p2cT, pw);
    score_kernel<<<NBLK_SCORE, 256, 0, stream>>>(p2cT, pw, best_s, best_i);
    merge_kernel<<<NBLK_MERGE, 256, 0, stream>>>(p1, p2cT, best_s, best_i, parts);
    final_kernel<<<1, 64, 0, stream>>>(parts, out);
}

// Round 22
// 50.056 us; speedup vs baseline: 1.2001x; 1.2001x over previous
//
#include <hip/hip_runtime.h>
#include <math.h>

#define NB 8
#define NC 3
#define HH 144
#define WW 144
#define NPAT 2304            // 48*48 patches per 144x144 image
#define NPTOT (NB * NPAT)    // 18432
#define MCAT 3024            // real candidates: 2304 + 576 + 144
#define MCATP 3072           // padded (48 guard cols, T = 1e30)
#define SPLITS 2             // candidate halves
#define CSPLIT 1536          // candidates per split
#define STEPS 12             // CSPLIT / (64 lanes * 2 cands)
#define PPT 6                // patches per 64-lane wave (aa2 -> 54 SGPRs)
#define WAVES 4              // waves per 256-thread block
#define PPB (PPT * WAVES)    // 24 patches per block
#define BLOCKS_PER_B (NPAT / PPB)                 // 96
#define NBLK_SCORE (NB * BLOCKS_PER_B * SPLITS)   // 1536 -> 6144 waves = 6/SIMD
#define NBLK_MERGE (NPTOT / 256)                  // 72

typedef float f2 __attribute__((ext_vector_type(2)));

__device__ __forceinline__ int iclamp(int v, int lo, int hi) {
    return v < lo ? lo : (v > hi ? hi : v);
}

// wave-uniform float -> SGPR (HK technique: readfirstlane hoisting)
__device__ __forceinline__ float to_sgpr(float v) {
    return __int_as_float(__builtin_amdgcn_readfirstlane(__float_as_int(v)));
}

// ---- fully fused bicubic resize (H then W pass per output pixel, frac=0.5
// constant taps; H-pass partials recomputed per pixel in identical fp32 order)
__global__ void resize_all(const float* __restrict__ gt,
                           float* __restrict__ gt2, float* __restrict__ gt4) {
    const int T2 = NB * NC * 72 * 72;
    const int T4 = NB * NC * 36 * 36;
    int idx = blockIdx.x * blockDim.x + threadIdx.x;
    if (idx >= T2 + T4) return;
    int scale, HO, WO;
    float* dst;
    int li;
    if (idx < T2) { scale = 2; HO = 72; WO = 72; dst = gt2; li = idx; }
    else          { scale = 4; HO = 36; WO = 36; dst = gt4; li = idx - T2; }
    int w  = li % WO;
    int h  = (li / WO) % HO;
    int bc = li / (WO * HO);
    const float* G = gt + (size_t)bc * HH * WW;
    int tr = scale * h + (scale >> 1) - 2;
    int tc = scale * w + (scale >> 1) - 2;
    int r0 = iclamp(tr + 0, 0, HH - 1) * WW;
    int r1 = iclamp(tr + 1, 0, HH - 1) * WW;
    int r2 = iclamp(tr + 2, 0, HH - 1) * WW;
    int r3 = iclamp(tr + 3, 0, HH - 1) * WW;
    float acc = 0.0f;
#pragma unroll
    for (int cc = 0; cc < 4; cc++) {
        int col = iclamp(tc + cc, 0, WW - 1);
        float hv = 0.0f;                       // H-pass value (same order as 2-pass)
        hv += -0.09375f * G[r0 + col];
        hv +=  0.59375f * G[r1 + col];
        hv +=  0.59375f * G[r2 + col];
        hv += -0.09375f * G[r3 + col];
        float wt = (cc == 0 || cc == 3) ? -0.09375f : 0.59375f;
        acc += wt * hv;                        // W-pass, same order
    }
    dst[li] = acc;
}

// gram of one 3x3 patch -> 9 values, /27 (same op order as reference)
__device__ __forceinline__ void patch_gram(const float* __restrict__ src, int H, int W,
                                           int b, int n, float* __restrict__ g) {
    int PW = W / 3;
    int ph = n / PW, pw = n % PW;
    float p[3][9];
#pragma unroll
    for (int c = 0; c < 3; c++) {
        const float* s = src + ((size_t)b * NC + c) * H * W + (size_t)(ph * 3) * W + pw * 3;
#pragma unroll
        for (int i = 0; i < 3; i++)
#pragma unroll
            for (int j = 0; j < 3; j++)
                p[c][i * 3 + j] = s[i * W + j];
    }
#pragma unroll
    for (int c = 0; c < 3; c++)
#pragma unroll
        for (int e = 0; e < 3; e++) {
            float s = 0.0f;
#pragma unroll
            for (int q = 0; q < 9; q++) s += p[c][q] * p[e][q];
            g[c * 3 + e] = s / 27.0f;
        }
}

// store candidate gram transposed [b][10][MCATP]; row 9 = T = 2*y2
__device__ __forceinline__ void store_cand(float* __restrict__ p2cT, int b, int m,
                                           const float g[9]) {
    float y2 = 0.0f;
#pragma unroll
    for (int j = 0; j < 9; j++) {
        p2cT[((size_t)b * 10 + j) * MCATP + m] = g[j];
        y2 += g[j] * g[j];
    }
    p2cT[((size_t)b * 10 + 9) * MCATP + m] = 2.0f * y2;
}

// ---- patches: pair-threads (x,gt together -> p1 + cand + packed aa2 row),
// gt2/gt4 threads (cand only), guard threads   [R15 global-best config]
__global__ void patch_all(const float* __restrict__ x, const float* __restrict__ gt,
                          const float* __restrict__ gt2, const float* __restrict__ gt4,
                          float* __restrict__ p1, float* __restrict__ p2cT,
                          float* __restrict__ pw) {
    const int R0 = NPTOT;        // pair threads
    const int R1 = NB * 576;     // gt2 -> m = 2304 + n
    const int R2 = NB * 144;     // gt4 -> m = 2880 + n
    int idx = blockIdx.x * blockDim.x + threadIdx.x;
    if (idx >= R0 + R1 + R2 + NB * 48) return;

    if (idx < R0) {
        int b = idx / NPAT, n = idx % NPAT;
        float g1[9], g2[9];
        patch_gram(x,  144, 144, b, n, g1);
        patch_gram(gt, 144, 144, b, n, g2);
        float* d = p1 + (size_t)idx * 9;
#pragma unroll
        for (int j = 0; j < 9; j++) d[j] = g1[j];
        store_cand(p2cT, b, n, g2);
        float* W = pw + (size_t)idx * 12;
#pragma unroll
        for (int j = 0; j < 9; j++) W[j] = -2.0f * (g1[j] + g2[j]);
        W[9]  = 0.0f;
        W[10] = 0.0f;
        W[11] = 0.0f;
        return;
    }
    if (idx < R0 + R1) {
        int li = idx - R0;
        int b = li / 576, n = li % 576;
        float g[9];
        patch_gram(gt2, 72, 72, b, n, g);
        store_cand(p2cT, b, NPAT + n, g);
        return;
    }
    if (idx < R0 + R1 + R2) {
        int li = idx - R0 - R1;
        int b = li / 144, n = li % 144;
        float g[9];
        patch_gram(gt4, 36, 36, b, n, g);
        store_cand(p2cT, b, NPAT + 576 + n, g);
        return;
    }
    // guard columns: cand = 0, T = 1e30 (never wins)
    {
        int li = idx - R0 - R1 - R2;
        int b = li / 48, m = MCAT + li % 48;
#pragma unroll
        for (int j = 0; j < 9; j++) p2cT[((size_t)b * 10 + j) * MCATP + m] = 0.0f;
        p2cT[((size_t)b * 10 + 9) * MCATP + m] = 1e30f;
    }
}

// ---- score + argmin over one candidate HALF, straight from L2 (NO LDS, NO
// barriers).  sc' = T + sum_j aa2[j]*v[j]; aa2 loaded from pw (bare loads)
// and hoisted to SGPRs.  f2 lane-pairs -> coalesced 512B/instr; every wave
// free-runs.  [R15 global-best config: 50.28us total, score ~35us]
__global__ __launch_bounds__(256) void score_kernel(const float* __restrict__ p2cT,
                                                    const float* __restrict__ pw,
                                                    float* __restrict__ best_s,
                                                    int* __restrict__ best_i) {
    int t     = threadIdx.x;
    int lane  = t & 63;
    int wv    = t >> 6;
    int blk   = blockIdx.x;
    int b     = blk / (SPLITS * BLOCKS_PER_B);
    int r     = blk % (SPLITS * BLOCKS_PER_B);
    int split = r / BLOCKS_PER_B;
    int bb    = r % BLOCKS_PER_B;
    int nbase = bb * PPB + wv * PPT;

    const float* PB = p2cT + (size_t)b * 10 * MCATP;

    // wave-uniform coefficients (bare loads) -> SGPRs (54 values)
    float aa2[PPT][9];
#pragma unroll
    for (int p = 0; p < PPT; p++) {
        const float* W = pw + (size_t)(b * NPAT + nbase + p) * 12;
#pragma unroll
        for (int j = 0; j < 9; j++) aa2[p][j] = to_sgpr(W[j]);
    }

    float best[PPT];
    int   besti[PPT];
#pragma unroll
    for (int p = 0; p < PPT; p++) { best[p] = INFINITY; besti[p] = 0x7fffffff; }

    int cb = split * CSPLIT;
#pragma unroll 1
    for (int st = 0; st < STEPS; st++) {
        int cl = cb + st * 128 + lane * 2;          // even float index, 8B aligned
        f2 Tv = *(const f2*)&PB[(size_t)9 * MCATP + cl];
        f2 s[PPT];
#pragma unroll
        for (int p = 0; p < PPT; p++) s[p] = Tv;
#pragma unroll
        for (int j = 0; j < 9; j++) {
            f2 v = *(const f2*)&PB[(size_t)j * MCATP + cl];
#pragma unroll
            for (int p = 0; p < PPT; p++) s[p] += aa2[p][j] * v;   // v_fmac v,s,v
        }
#pragma unroll
        for (int p = 0; p < PPT; p++) {
            // ascending index within lane: strict < keeps first min
            if (s[p].x < best[p]) { best[p] = s[p].x; besti[p] = cl; }
            if (s[p].y < best[p]) { best[p] = s[p].y; besti[p] = cl + 1; }
        }
    }

    // lexicographic (score, idx) min across the 64 lanes
#pragma unroll
    for (int p = 0; p < PPT; p++) {
#pragma unroll
        for (int m = 1; m < 64; m <<= 1) {
            float ob = __shfl_xor(best[p], m);
            int   oi = __shfl_xor(besti[p], m);
            if (ob < best[p] || (ob == best[p] && oi < besti[p])) { best[p] = ob; besti[p] = oi; }
        }
        if (lane == 0) {
            size_t o = (size_t)split * NPTOT + (size_t)b * NPAT + nbase + p;
            best_s[o] = best[p];
            best_i[o] = besti[p];
        }
    }
}

// ---- merge the two split results + per-patch L1 + per-block partial sum
__global__ __launch_bounds__(256) void merge_kernel(const float* __restrict__ p1,
                                                    const float* __restrict__ p2cT,
                                                    const float* __restrict__ best_s,
                                                    const int* __restrict__ best_i,
                                                    float* __restrict__ parts) {
    __shared__ float wsum[4];
    int t  = threadIdx.x;
    int gp = blockIdx.x * 256 + t;
    int b  = gp / NPAT;
    float s0 = best_s[gp];
    int   i0 = best_i[gp];
    float s1 = best_s[NPTOT + gp];
    int   i1 = best_i[NPTOT + gp];
    int bi = (s1 < s0) ? i1 : i0;   // ties -> i0 (half0 indices always lower)
    const float* P1 = p1 + (size_t)gp * 9;
    const float* PB = p2cT + (size_t)b * 10 * MCATP;
    float l = 0.0f;
#pragma unroll
    for (int j = 0; j < 9; j++) l += fabsf(P1[j] - PB[(size_t)j * MCATP + bi]);
#pragma unroll
    for (int m = 1; m < 64; m <<= 1) l += __shfl_xor(l, m);
    if ((t & 63) == 0) wsum[t >> 6] = l;
    __syncthreads();
    if (t == 0) parts[blockIdx.x] = (wsum[0] + wsum[1]) + (wsum[2] + wsum[3]);
}

__global__ void final_kernel(const float* __restrict__ parts, float* __restrict__ out) {
    int lane = threadIdx.x;
    float s = 0.0f;
    for (int i = lane; i < NBLK_MERGE; i += 64) s += parts[i];
#pragma unroll
    for (int m = 1; m < 64; m <<= 1) s += __shfl_xor(s, m);
    if (lane == 0) out[0] = s / 165888.0f;   // mean over 8*2304*9
}

extern "C" void kernel_launch(void* const* d_in, const int* in_sizes, int n_in,
                              void* d_out, int out_size, void* d_ws, size_t ws_size,
                              hipStream_t stream) {
    const float* x  = (const float*)d_in[0];
    const float* gt = (const float*)d_in[1];
    float* out = (float*)d_out;

    float* ws     = (float*)d_ws;
    float* gt2    = ws;                               // [8,3,72,72]   = 124416
    float* gt4    = gt2  + NB * NC * 72 * 72;         // [8,3,36,36]   =  31104
    float* p1     = gt4  + NB * NC * 36 * 36;         // [18432,9]     = 165888
    float* p2cT   = p1 + (size_t)NPTOT * 9;           // [8,10,3072]   = 245760
    float* pw     = p2cT + (size_t)NB * 10 * MCATP;   // [18432,12]    = 221184
    float* best_s = pw + (size_t)NPTOT * 12;          // [2,18432]     =  36864
    int*   best_i = (int*)(best_s + SPLITS * NPTOT);  // [2,18432]     =  36864
    float* parts  = (float*)(best_i + SPLITS * NPTOT);// [72]

    {
        int tot = NB * NC * 72 * 72 + NB * NC * 36 * 36;   // 155520
        resize_all<<<(tot + 255) / 256, 256, 0, stream>>>(gt, gt2, gt4);
    }
    {
        int tot = NPTOT + NB * 576 + NB * 144 + NB * 48;   // 24576
        patch_all<<<(tot + 255) / 256, 256, 0, stream>>>(x, gt, gt2, gt4, p1, p2cT, pw);
    }
    score_kernel<<<NBLK_SCORE, 256, 0, stream>>>(p2cT, pw, best_s, best_i);
    merge_kernel<<<NBLK_MERGE, 256, 0, stream>>>(p1, p2cT, best_s, best_i, parts);
    final_kernel<<<1, 64, 0, stream>>>(parts, out);
}